// Round 1
// baseline (106.827 us; speedup 1.0000x reference)
//
#include <hip/hip_runtime.h>
#include <hip/hip_bf16.h>

#define BATCH 16384
#define DIM   512
#define NPG   64
#define NPAIR 4096
#define NA    128   // 2*NPG rows of combined A

typedef float f32x4 __attribute__((ext_vector_type(4)));
typedef short s16x8 __attribute__((ext_vector_type(8)));

static __device__ __forceinline__ unsigned short f2bf(float f) {
    union { float f; unsigned u; } v; v.f = f;
    unsigned r = (v.u + 0x7FFFu + ((v.u >> 16) & 1u)) >> 16;
    return (unsigned short)r;
}

// K1: A[j][d] = sum_k proto[j][k] * W[d][koff+k],  j in [0,128), d in [0,512)
__global__ void k1_mixA(const float* __restrict__ proto, const float* __restrict__ W,
                        float* __restrict__ Af, unsigned short* __restrict__ Ab) {
    int gid = blockIdx.x * blockDim.x + threadIdx.x;   // 65536 threads
    int j = gid & (NA - 1);
    int d = gid >> 7;
    int koff = (j < NPG) ? 0 : DIM;
    const float4* pr = (const float4*)(proto + j * DIM);
    const float4* wr = (const float4*)(W + d * (2 * DIM) + koff);
    float a0 = 0.f, a1 = 0.f, a2 = 0.f, a3 = 0.f;
#pragma unroll 4
    for (int k4 = 0; k4 < DIM / 4; ++k4) {
        float4 p = pr[k4], w = wr[k4];
        a0 += p.x * w.x; a1 += p.y * w.y; a2 += p.z * w.z; a3 += p.w * w.w;
    }
    float a = (a0 + a1) + (a2 + a3);
    Af[j * DIM + d] = a;
    Ab[j * DIM + d] = f2bf(a);
}

// K2: pp[j*64+l] = || A[j] + A[64+l] + b ||^2   (one wave per pair)
__global__ void k2_pp(const float* __restrict__ Af, const float* __restrict__ bm,
                      float* __restrict__ pp) {
    int wave = (blockIdx.x * blockDim.x + threadIdx.x) >> 6;  // 4096 waves
    int lane = threadIdx.x & 63;
    int j = wave >> 6, l = wave & 63;
    const float4* r0 = (const float4*)(Af + j * DIM);
    const float4* r1 = (const float4*)(Af + (NPG + l) * DIM);
    const float4* bb = (const float4*)bm;
    float acc = 0.f;
#pragma unroll
    for (int i = 0; i < 2; ++i) {
        int idx = lane * 2 + i;
        float4 v0 = r0[idx], v1 = r1[idx], vb = bb[idx];
        float s;
        s = v0.x + v1.x + vb.x; acc += s * s;
        s = v0.y + v1.y + vb.y; acc += s * s;
        s = v0.z + v1.z + vb.z; acc += s * s;
        s = v0.w + v1.w + vb.w; acc += s * s;
    }
#pragma unroll
    for (int off = 32; off > 0; off >>= 1) acc += __shfl_xor(acc, off);
    if (lane == 0) pp[wave] = acc;
}

// K3: xx[b] = ||x_b||^2 ; w[b] = x_b . b_mix   (one wave per row)
__global__ void k3_xxw(const float* __restrict__ x, const float* __restrict__ bm,
                       float* __restrict__ xx, float* __restrict__ w) {
    int wave = (blockIdx.x * blockDim.x + threadIdx.x) >> 6;  // 16384 waves
    int lane = threadIdx.x & 63;
    const float4* xr = (const float4*)(x + (size_t)wave * DIM);
    const float4* bb = (const float4*)bm;
    float axx = 0.f, aw = 0.f;
#pragma unroll
    for (int i = 0; i < 2; ++i) {
        int idx = lane * 2 + i;
        float4 v = xr[idx], vb = bb[idx];
        axx += v.x * v.x + v.y * v.y + v.z * v.z + v.w * v.w;
        aw  += v.x * vb.x + v.y * vb.y + v.z * vb.z + v.w * vb.w;
    }
#pragma unroll
    for (int off = 32; off > 0; off >>= 1) {
        axx += __shfl_xor(axx, off);
        aw  += __shfl_xor(aw, off);
    }
    if (lane == 0) { xx[wave] = axx; w[wave] = aw; }
}

// K4: U[16384][128] = X @ A^T via bf16 MFMA 16x16x32. 4 waves/block, 16 rows/wave.
__global__ void k4_gemm(const float* __restrict__ x, const unsigned short* __restrict__ Ab,
                        float* __restrict__ U) {
    int lane = threadIdx.x & 63;
    int wv = threadIdx.x >> 6;
    int m0 = blockIdx.x * 64 + wv * 16;
    int r = lane & 15, g = lane >> 4;
    f32x4 acc[8];
#pragma unroll
    for (int ct = 0; ct < 8; ++ct) acc[ct] = (f32x4){0.f, 0.f, 0.f, 0.f};
    const float* xrow = x + (size_t)(m0 + r) * DIM;
    for (int k0 = 0; k0 < DIM; k0 += 32) {
        int kb = k0 + g * 8;
        float4 xa = *(const float4*)(xrow + kb);
        float4 xb = *(const float4*)(xrow + kb + 4);
        s16x8 xf;
        xf[0] = (short)f2bf(xa.x); xf[1] = (short)f2bf(xa.y);
        xf[2] = (short)f2bf(xa.z); xf[3] = (short)f2bf(xa.w);
        xf[4] = (short)f2bf(xb.x); xf[5] = (short)f2bf(xb.y);
        xf[6] = (short)f2bf(xb.z); xf[7] = (short)f2bf(xb.w);
#pragma unroll
        for (int ct = 0; ct < 8; ++ct) {
            s16x8 bf = *(const s16x8*)(Ab + (ct * 16 + r) * DIM + kb);
            acc[ct] = __builtin_amdgcn_mfma_f32_16x16x32_bf16(xf, bf, acc[ct], 0, 0, 0);
        }
    }
    // C/D layout (verified m89): col = lane&15, row = (lane>>4)*4 + reg
#pragma unroll
    for (int ct = 0; ct < 8; ++ct)
#pragma unroll
        for (int rr = 0; rr < 4; ++rr)
            U[(size_t)(m0 + g * 4 + rr) * NA + ct * 16 + r] = acc[ct][rr];
}

// K5: out[b][j*64+l] = xx[b] + pp[j*64+l] - 2*(U[b][j] + U[b][64+l] + w[b])
__global__ void k5_out(const float* __restrict__ U, const float* __restrict__ xx,
                       const float* __restrict__ w, const float* __restrict__ pp,
                       float* __restrict__ out) {
    int b = blockIdx.x;
    int t = threadIdx.x;
    float base0 = xx[b] - 2.0f * w[b];
    const float* Ur = U + (size_t)b * NA;
    float* orow = out + (size_t)b * NPAIR;
#pragma unroll
    for (int i = 0; i < 4; ++i) {
        int idx = i * 1024 + t * 4;
        int j = idx >> 6, l = idx & 63;
        float uj = Ur[j];
        float4 v4 = *(const float4*)(Ur + NPG + l);
        float4 p4 = *(const float4*)(pp + idx);
        float base = base0 - 2.0f * uj;
        float4 o;
        o.x = base + p4.x - 2.0f * v4.x;
        o.y = base + p4.y - 2.0f * v4.y;
        o.z = base + p4.z - 2.0f * v4.z;
        o.w = base + p4.w - 2.0f * v4.w;
        *(float4*)(orow + idx) = o;
    }
}

extern "C" void kernel_launch(void* const* d_in, const int* in_sizes, int n_in,
                              void* d_out, int out_size, void* d_ws, size_t ws_size,
                              hipStream_t stream) {
    const float* x     = (const float*)d_in[0];   // [16384, 512]
    const float* proto = (const float*)d_in[1];   // [2, 64, 512] -> flat [128, 512]
    const float* Wmix  = (const float*)d_in[2];   // [512, 1024]
    const float* bmix  = (const float*)d_in[3];   // [512]
    float* out = (float*)d_out;

    float* ws = (float*)d_ws;
    float*          Af = ws;                                   // 65536 f32
    unsigned short* Ab = (unsigned short*)(ws + 65536);        // 65536 bf16
    float*          pp = ws + 65536 + 32768;                   // 4096
    float*          xx = pp + NPAIR;                           // 16384
    float*          w  = xx + BATCH;                           // 16384
    float*          U  = w + BATCH;                            // 16384*128

    k1_mixA<<<256, 256, 0, stream>>>(proto, Wmix, Af, Ab);
    k2_pp  <<<1024, 256, 0, stream>>>(Af, bmix, pp);
    k3_xxw <<<4096, 256, 0, stream>>>(x, bmix, xx, w);
    k4_gemm<<<256, 256, 0, stream>>>(x, Ab, U);
    k5_out <<<BATCH, 256, 0, stream>>>(U, xx, w, pp, out);
}